// Round 14
// baseline (49.593 us; speedup 1.0000x reference)
//
#include <hip/hip_runtime.h>
#include <math.h>

// Analytic collapse (verified R1-R12, absmax 3.9e-3):
//   t = tanh(W1 @ x_n); v = tanh(W2 @ t); z = Wout . v
//   a = sum_h sob[h]*sin(2*pi*soa[h]*z/7);  out = sign(a)*4*z*e^|a|/(4e^|a|+5)
//
// R14 = R13 with the compile fix (stray ternary removed). Identical
// fp32-emulated MFMA arithmetic (bf16 3-level split, 6 products per
// accumulator, same per-acc order -> bit-identical). Scheduling:
//   1. ROUND-ROBIN MFMA emission: products p0..p5 x ot0..3 (same-acc MFMAs
//      4 apart) -> dependent-chain latency covered at 2 waves/SIMD.
//   2. Phase body: barrier -> readA8(next) -> cluster(cur) -> packB(next) ->
//      stage(+3)/issueX -> vmcnt -> barrier.
//   Staging 3-ahead; counted vmcnt 5/3/0; no setprio/sched_barrier.

typedef __bf16 bf16x8 __attribute__((ext_vector_type(8)));
typedef float  f32x16 __attribute__((ext_vector_type(16)));
typedef unsigned int u32;
typedef unsigned short u16;

union FRAG { uint4 q; bf16x8 v; };

#define NROWS 65536

#define WAITV(N) asm volatile("s_waitcnt vmcnt(" #N ")" ::: "memory")
#define BARRIER() asm volatile("s_barrier" ::: "memory")

// ---- bf16 3-level split: x = h + m + l + O(2^-25 |x|) ----
__device__ __forceinline__ void split3(float x, u32& h, u32& m, u32& l) {
    u32 u = __float_as_uint(x);
    h = u >> 16;
    float hf = __uint_as_float(u & 0xFFFF0000u);
    float r1 = x - hf;                       // exact
    u32 u1 = __float_as_uint(r1);
    m = u1 >> 16;
    float mf = __uint_as_float(u1 & 0xFFFF0000u);
    float r2 = r1 - mf;                      // exact
    u32 u2 = __float_as_uint(r2);
    l = (u2 + 0x7FFFu + ((u2 >> 16) & 1u)) >> 16;   // RNE
}

__device__ __forceinline__ void pack2(float a, float b, u32& H, u32& M, u32& L) {
    u32 h0, m0, l0, h1, m1, l1;
    split3(a, h0, m0, l0); split3(b, h1, m1, l1);
    H = h0 | (h1 << 16); M = m0 | (m1 << 16); L = l0 | (l1 << 16);
}

__device__ __forceinline__ float fast_tanh(float x) {
    float e = __expf(2.f * x);
    return 1.f - 2.f * __builtin_amdgcn_rcpf(e + 1.f);  // inf-safe, ~4e-7 abs err
}

__device__ __forceinline__ void glds16(const uint4* g, uint4* l) {
    __builtin_amdgcn_global_load_lds(
        (const __attribute__((address_space(1))) void*)g,
        (__attribute__((address_space(3))) void*)l, 16, 0, 0);
}

// ====== pre-kernel: split W1/W2 into fragment-major bf16 planes in d_ws ======
__global__ void presplit(const float* __restrict__ W1,
                         const float* __restrict__ W2,
                         u16* __restrict__ ws)
{
    int t = blockIdx.x * 256 + threadIdx.x;   // 0..6143
    const float* src;
    size_t dbase, lstep;
    if (t < 4096) {
        int f = t >> 6, lane = t & 63;
        int c = f >> 4, s = (f >> 2) & 3, ot = f & 3;
        int l31 = lane & 31, hi = lane >> 5;
        src   = W1 + (size_t)(32 * ot + l31) * 256 + c * 64 + s * 16 + 8 * hi;
        dbase = (size_t)(f * 64 + lane) * 8;
        lstep = 32768;
    } else {
        int t2 = t - 4096;
        int f = t2 >> 6, lane = t2 & 63;
        int s = f >> 2, ot = f & 3;
        int l31 = lane & 31, hi = lane >> 5;
        src   = W2 + (size_t)(32 * ot + l31) * 128 + s * 16 + 8 * hi;
        dbase = 98304 + (size_t)(f * 64 + lane) * 8;
        lstep = 16384;
    }
    u16 H[8], M[8], L[8];
    #pragma unroll
    for (int j = 0; j < 8; ++j) {
        u32 h, m, l;
        split3(src[j], h, m, l);
        H[j] = (u16)h; M[j] = (u16)m; L[j] = (u16)l;
    }
    #pragma unroll
    for (int j = 0; j < 8; ++j) {
        ws[dbase + j]             = H[j];
        ws[dbase + lstep + j]     = M[j];
        ws[dbase + 2 * lstep + j] = L[j];
    }
}

// ================= main kernel ==============================================
// 256 thr = 4 waves; 128 rows/block; wave w owns rows 32w..32w+31; grid = 512.
__global__ __launch_bounds__(256, 2)
void fused_mlp14(const float* __restrict__ x,
                 const u16*   __restrict__ wsp,
                 const float* __restrict__ Wout,
                 const float* __restrict__ soa,
                 const float* __restrict__ sob,
                 float* __restrict__ out)
{
    __shared__ uint4 Ab[4][768];              // 48 KB: 4-deep A-batch rotation
    __shared__ uint4 tl[2048];                // 32 KB: tf l-plane [w][s][lane]

    const int tid  = threadIdx.x;
    const int w    = tid >> 6;                // 0..3
    const int lane = tid & 63;
    const int l31  = lane & 31;
    const int hi   = lane >> 5;
    const int nloc = (w << 5) + l31;
    const int n0g  = blockIdx.x * 128;

    const uint4*  wf   = reinterpret_cast<const uint4*>(wsp);
    const float4* xrow = reinterpret_cast<const float4*>(x) + (size_t)(n0g + nloc) * 64;

    // wave w stages items i = 3w..3w+2 (of 12) of K16-step g's A-batch
    auto stage = [&](int g, uint4* dst) {
        #pragma unroll
        for (int j = 0; j < 3; ++j) {
            int i  = w * 3 + j;
            int lv = i >> 2, ot = i & 3;
            const uint4* src = (g < 16)
                ? wf + lv * 4096 + (g * 4 + ot) * 64 + lane
                : wf + 12288 + lv * 2048 + ((g - 16) * 4 + ot) * 64 + lane;
            glds16(src, dst + i * 64);
        }
    };

    f32x16 acc[4];
    #pragma unroll
    for (int ot = 0; ot < 4; ++ot) acc[ot] = (f32x16)0.f;

    FRAG Rev[8], Rod[8];                      // A-frag register ping-pong (Ah,Am)
    FRAG Bevh, Bevm, Bevl, Bodh, Bodm, Bodl;
    float4 x0a, x0b, x1a, x1b;

    auto readA8 = [&](const uint4* buf, FRAG* R) {
        #pragma unroll
        for (int i = 0; i < 8; ++i) R[i].q = buf[i * 64 + lane];
    };
    auto packB = [&](const float4& a, const float4& b, FRAG& Bh, FRAG& Bm, FRAG& Bl) {
        pack2(a.x, a.y, Bh.q.x, Bm.q.x, Bl.q.x);
        pack2(a.z, a.w, Bh.q.y, Bm.q.y, Bl.q.y);
        pack2(b.x, b.y, Bh.q.z, Bm.q.z, Bl.q.z);
        pack2(b.z, b.w, Bh.q.w, Bm.q.w, Bl.q.w);
    };
    // ROUND-ROBIN cluster: products p0..p5 emitted across ot0..3 (same-acc
    // MFMAs 4 apart). Per-accumulator order identical to R4-R12:
    //   (R,Bh),(R,Bm),(R4,Bh),(R4,Bm),(R,Bl),(Al,Bh)
    auto clusterRR = [&](const uint4* Ac, FRAG* R, f32x16* A,
                         const FRAG& Bh, const FRAG& Bm, const FRAG& Bl) {
        FRAG Al[4];
        #pragma unroll
        for (int ot = 0; ot < 4; ++ot) Al[ot].q = Ac[(8 + ot) * 64 + lane];
        #pragma unroll
        for (int ot = 0; ot < 4; ++ot)
            A[ot] = __builtin_amdgcn_mfma_f32_32x32x16_bf16(R[ot].v, Bh.v, A[ot], 0,0,0);
        #pragma unroll
        for (int ot = 0; ot < 4; ++ot)
            A[ot] = __builtin_amdgcn_mfma_f32_32x32x16_bf16(R[ot].v, Bm.v, A[ot], 0,0,0);
        #pragma unroll
        for (int ot = 0; ot < 4; ++ot)
            A[ot] = __builtin_amdgcn_mfma_f32_32x32x16_bf16(R[4 + ot].v, Bh.v, A[ot], 0,0,0);
        #pragma unroll
        for (int ot = 0; ot < 4; ++ot)
            A[ot] = __builtin_amdgcn_mfma_f32_32x32x16_bf16(R[4 + ot].v, Bm.v, A[ot], 0,0,0);
        #pragma unroll
        for (int ot = 0; ot < 4; ++ot)
            A[ot] = __builtin_amdgcn_mfma_f32_32x32x16_bf16(R[ot].v, Bl.v, A[ot], 0,0,0);
        #pragma unroll
        for (int ot = 0; ot < 4; ++ot)
            A[ot] = __builtin_amdgcn_mfma_f32_32x32x16_bf16(Al[ot].v, Bh.v, A[ot], 0,0,0);
    };

    // ---- prologue: stage 0,1,2 (3-ahead); x(0),x(1); A(0)->Rev; B(0) ----
    stage(0, Ab[0]);
    x0a = xrow[hi * 2]; x0b = xrow[hi * 2 + 1];
    stage(1, Ab[1]);
    x1a = xrow[4 + hi * 2]; x1b = xrow[4 + hi * 2 + 1];
    stage(2, Ab[2]);
    WAITV(3);            // stage0 + x0 + stage1 + x1 drained (stage2 in flight)
    BARRIER();
    readA8(Ab[0], Rev);
    packB(x0a, x0b, Bevh, Bevm, Bevl);

    // =================== layer 1 phases 0..11 (4-phase body) =================
    // invariant at phase g entry: Rev/Rod(g parity) = A(g); B(g) packed;
    // x slot (g+1)&1 = x(g+1); batches g..g+2 staged.
    #pragma unroll 1
    for (int i = 0; i < 3; ++i) {
        const int P = 4 * i;
        // phase P (even)
        readA8(Ab[(P + 1) & 3], Rod);
        clusterRR(Ab[P & 3], Rev, acc, Bevh, Bevm, Bevl);
        packB(x1a, x1b, Bodh, Bodm, Bodl);                 // B(P+1)
        stage(P + 3, Ab[(P + 3) & 3]);
        { int g = P + 2; x0a = xrow[g * 4 + hi * 2]; x0b = xrow[g * 4 + hi * 2 + 1]; }
        WAITV(5); BARRIER();
        // phase P+1 (odd)
        readA8(Ab[(P + 2) & 3], Rev);
        clusterRR(Ab[(P + 1) & 3], Rod, acc, Bodh, Bodm, Bodl);
        packB(x0a, x0b, Bevh, Bevm, Bevl);                 // B(P+2)
        stage(P + 4, Ab[(P + 4) & 3]);
        { int g = P + 3; x1a = xrow[g * 4 + hi * 2]; x1b = xrow[g * 4 + hi * 2 + 1]; }
        WAITV(5); BARRIER();
        // phase P+2 (even)
        readA8(Ab[(P + 3) & 3], Rod);
        clusterRR(Ab[(P + 2) & 3], Rev, acc, Bevh, Bevm, Bevl);
        packB(x1a, x1b, Bodh, Bodm, Bodl);                 // B(P+3)
        stage(P + 5, Ab[(P + 5) & 3]);
        { int g = P + 4; x0a = xrow[g * 4 + hi * 2]; x0b = xrow[g * 4 + hi * 2 + 1]; }
        WAITV(5); BARRIER();
        // phase P+3 (odd)
        readA8(Ab[(P + 4) & 3], Rev);
        clusterRR(Ab[(P + 3) & 3], Rod, acc, Bodh, Bodm, Bodl);
        packB(x0a, x0b, Bevh, Bevm, Bevl);                 // B(P+4)
        stage(P + 6, Ab[(P + 6) & 3]);
        { int g = P + 5; x1a = xrow[g * 4 + hi * 2]; x1b = xrow[g * 4 + hi * 2 + 1]; }
        WAITV(5); BARRIER();
    }

    // ---- phases 12..15 ----
    // entry: Rev=A(12), Bev=B(12), x1=x(13)
    readA8(Ab[13 & 3], Rod);                               // phase 12
    clusterRR(Ab[12 & 3], Rev, acc, Bevh, Bevm, Bevl);
    packB(x1a, x1b, Bodh, Bodm, Bodl);                     // B(13)
    stage(15, Ab[15 & 3]);
    x0a = xrow[14 * 4 + hi * 2]; x0b = xrow[14 * 4 + hi * 2 + 1];
    WAITV(5); BARRIER();

    readA8(Ab[14 & 3], Rev);                               // phase 13
    clusterRR(Ab[13 & 3], Rod, acc, Bodh, Bodm, Bodl);
    packB(x0a, x0b, Bevh, Bevm, Bevl);                     // B(14)
    stage(16, Ab[16 & 3]);
    x1a = xrow[15 * 4 + hi * 2]; x1b = xrow[15 * 4 + hi * 2 + 1];
    WAITV(5); BARRIER();

    readA8(Ab[15 & 3], Rod);                               // phase 14
    clusterRR(Ab[14 & 3], Rev, acc, Bevh, Bevm, Bevl);
    packB(x1a, x1b, Bodh, Bodm, Bodl);                     // B(15)
    stage(17, Ab[17 & 3]);
    WAITV(3); BARRIER();

    readA8(Ab[16 & 3], Rev);                               // phase 15: A(16)
    clusterRR(Ab[15 & 3], Rod, acc, Bodh, Bodm, Bodl);
    stage(18, Ab[18 & 3]);
    WAITV(3); BARRIER();

    // ====== t = tanh(D1); tf h,m in regs; l-plane -> wave-private LDS ======
    FRAG tfh[8], tfm[8];
    #pragma unroll
    for (int ft = 0; ft < 4; ++ft) {
        #pragma unroll
        for (int sub = 0; sub < 2; ++sub) {
            int s = 2 * ft + sub;
            float tv[8];
            u32 th[8], tm[8], tlv[8];
            #pragma unroll
            for (int j = 0; j < 8; ++j) {
                tv[j] = fast_tanh(acc[ft][8 * sub + j]);
                split3(tv[j], th[j], tm[j], tlv[j]);
            }
            #pragma unroll
            for (int lv = 0; lv < 3; ++lv) {
                const u32* t_ = (lv == 0) ? th : (lv == 1) ? tm : tlv;
                u32 P0 = t_[0] | (t_[1] << 16);
                u32 P1 = t_[2] | (t_[3] << 16);
                u32 Q0 = t_[4] | (t_[5] << 16);
                u32 Q1 = t_[6] | (t_[7] << 16);
                u32 sP0 = (u32)__shfl_xor((int)P0, 32);
                u32 sP1 = (u32)__shfl_xor((int)P1, 32);
                u32 sQ0 = (u32)__shfl_xor((int)Q0, 32);
                u32 sQ1 = (u32)__shfl_xor((int)Q1, 32);
                uint4 q;
                q.x = hi ? sQ0 : P0;
                q.y = hi ? sQ1 : P1;
                q.z = hi ? Q0 : sP0;
                q.w = hi ? Q1 : sP1;
                if (lv == 0)      tfh[s].q = q;
                else if (lv == 1) tfm[s].q = q;
                else              tl[(w << 9) + (s << 6) + lane] = q;
            }
        }
    }

    // =================== layer 2: phases 16..23 ==============================
    f32x16 acc2[4];
    #pragma unroll
    for (int ot = 0; ot < 4; ++ot) acc2[ot] = (f32x16)0.f;

    FRAG Blev, Blod;
    Blev.q = tl[(w << 9) + lane];                          // l(0)

    readA8(Ab[1], Rod);                                    // phase 16: A(17)
    Blod.q = tl[(w << 9) + (1 << 6) + lane];
    clusterRR(Ab[0], Rev, acc2, tfh[0], tfm[0], Blev);
    stage(19, Ab[3]);
    WAITV(3); BARRIER();

    readA8(Ab[2], Rev);                                    // phase 17: A(18)
    Blev.q = tl[(w << 9) + (2 << 6) + lane];
    clusterRR(Ab[1], Rod, acc2, tfh[1], tfm[1], Blod);
    stage(20, Ab[0]);
    WAITV(3); BARRIER();

    readA8(Ab[3], Rod);                                    // phase 18: A(19)
    Blod.q = tl[(w << 9) + (3 << 6) + lane];
    clusterRR(Ab[2], Rev, acc2, tfh[2], tfm[2], Blev);
    stage(21, Ab[1]);
    WAITV(3); BARRIER();

    readA8(Ab[0], Rev);                                    // phase 19: A(20)
    Blev.q = tl[(w << 9) + (4 << 6) + lane];
    clusterRR(Ab[3], Rod, acc2, tfh[3], tfm[3], Blod);
    stage(22, Ab[2]);
    WAITV(3); BARRIER();

    readA8(Ab[1], Rod);                                    // phase 20: A(21)
    Blod.q = tl[(w << 9) + (5 << 6) + lane];
    clusterRR(Ab[0], Rev, acc2, tfh[4], tfm[4], Blev);
    stage(23, Ab[3]);
    WAITV(3); BARRIER();

    readA8(Ab[2], Rev);                                    // phase 21: A(22)
    Blev.q = tl[(w << 9) + (6 << 6) + lane];
    clusterRR(Ab[1], Rod, acc2, tfh[5], tfm[5], Blod);
    WAITV(0); BARRIER();

    readA8(Ab[3], Rod);                                    // phase 22: A(23)
    Blod.q = tl[(w << 9) + (7 << 6) + lane];
    clusterRR(Ab[2], Rev, acc2, tfh[6], tfm[6], Blev);
    BARRIER();

    clusterRR(Ab[3], Rod, acc2, tfh[7], tfm[7], Blod);     // phase 23

    // ====== epilogue: v = tanh(D2); z = Wout . v ; analytic tail ======
    float zp = 0.f;
    #pragma unroll
    for (int ft = 0; ft < 4; ++ft) {
        #pragma unroll
        for (int rg = 0; rg < 4; ++rg) {
            const float4 wo = *reinterpret_cast<const float4*>(Wout + 32 * ft + 8 * rg + 4 * hi);
            zp += fast_tanh(acc2[ft][4 * rg + 0]) * wo.x
                + fast_tanh(acc2[ft][4 * rg + 1]) * wo.y
                + fast_tanh(acc2[ft][4 * rg + 2]) * wo.z
                + fast_tanh(acc2[ft][4 * rg + 3]) * wo.w;
        }
    }
    float z = zp + __shfl_xor(zp, 32);

    if (lane < 32) {
        const float CC = 0.8975979010256552f;   // 2*pi/7
        float a = 0.f;
        #pragma unroll
        for (int k = 0; k < 32; ++k)
            a += sob[k] * sinf(CC * soa[k] * z);
        float mm  = expf(fabsf(a));
        float res = 4.f * z * mm / (4.f * mm + 5.f);
        out[n0g + (w << 5) + lane] = (a > 0.f) ? res : ((a < 0.f) ? -res : 0.f);
    }
}

extern "C" void kernel_launch(void* const* d_in, const int* in_sizes, int n_in,
                              void* d_out, int out_size, void* d_ws, size_t ws_size,
                              hipStream_t stream) {
    const float* x    = (const float*)d_in[0];
    const float* W1   = (const float*)d_in[1];
    const float* W2   = (const float*)d_in[2];
    const float* Wout = (const float*)d_in[3];
    const float* soa  = (const float*)d_in[8];
    const float* sob  = (const float*)d_in[9];
    float* outp = (float*)d_out;
    u16* ws = (u16*)d_ws;   // needs 294912 B

    hipLaunchKernelGGL(presplit, dim3(24), dim3(256), 0, stream, W1, W2, ws);
    hipLaunchKernelGGL(fused_mlp14, dim3(NROWS / 128), dim3(256), 0, stream,
                       x, ws, Wout, soa, sob, outp);
}